// Round 4
// baseline (940.616 us; speedup 1.0000x reference)
//
#include <hip/hip_runtime.h>
#include <math.h>

#define N_ATOMS 20000
#define G_GRAPHS 500
#define NPG 40
#define DEG 16
#define E_EDGES (N_ATOMS * DEG)
#define EPM (NPG * DEG)          // 640 edges per molecule
#define HID 128
#define NF 128
#define TBL2 160                 // cubic-interp table rows (grid points)
#define TROWS (TBL2 + 2)         // +1 extrapolated row each end for Catmull-Rom
#define CUTOFF 10.0f
#define LOG2F_ 0.6931471805599453f

__device__ __forceinline__ float ssp_f(float x) {
  float ax = fabsf(x);
  return fmaxf(x, 0.0f) + log1pf(expf(-ax)) - LOG2F_;
}

// ---------------- distances -> pre-scaled table coordinate ----------------
__global__ void k_dist(const float* __restrict__ pos, const int* __restrict__ ei,
                       float* __restrict__ ftb) {
  int e = blockIdx.x * blockDim.x + threadIdx.x;
  if (e >= E_EDGES) return;
  int r = ei[e], c = ei[E_EDGES + e];
  float dx = pos[3 * r + 0] - pos[3 * c + 0];
  float dy = pos[3 * r + 1] - pos[3 * c + 1];
  float dz = pos[3 * r + 2] - pos[3 * c + 2];
  ftb[e] = sqrtf(dx * dx + dy * dy + dz * dz) * ((float)(TBL2 - 1) / CUTOFF);
}

// ---------------- embedding gather ----------------
__global__ void k_embed(const float* __restrict__ emb, const int* __restrict__ z,
                        float* __restrict__ h) {
  int t = blockIdx.x * blockDim.x + threadIdx.x;
  if (t >= N_ATOMS * HID) return;
  int i = t >> 7, c = t & 127;
  h[t] = emb[z[i] * HID + c];
}

// ---- filter tables (all 3 layers), rows r=-1..TBL2 at d=(r)*h, stored at r+1 ----
__global__ void k_table(const float* __restrict__ w1_, const float* __restrict__ b1_,
                        const float* __restrict__ w2_, const float* __restrict__ b2_,
                        float* __restrict__ table_) {
  __shared__ float ea[16][NF];
  __shared__ float hidv[16][NF];
  int l = blockIdx.y;
  const float* w1 = w1_ + (size_t)l * NF * NF;
  const float* b1 = b1_ + (size_t)l * NF;
  const float* w2 = w2_ + (size_t)l * NF * NF;
  const float* b2 = b2_ + (size_t)l * NF;
  float* table = table_ + (size_t)l * TROWS * NF;
  int j = threadIdx.x;
  int rbase = blockIdx.x * 16;
  const float h = CUTOFF / (float)(TBL2 - 1);
  const float delta = CUTOFF / (float)(NF - 1);
  const float coeff = -0.5f / (delta * delta);
#pragma unroll
  for (int rr = 0; rr < 16; ++rr) {
    float d = ((float)(rbase + rr) - 1.0f) * h;  // stored index s -> d=(s-1)*h
    float t = d - delta * (float)j;
    ea[rr][j] = expf(coeff * t * t);
  }
  __syncthreads();
  float b1j = b1[j];
  float acc[16];
#pragma unroll
  for (int rr = 0; rr < 16; ++rr) acc[rr] = b1j;
  for (int k = 0; k < NF; ++k) {
    float wv = w1[k * NF + j];
#pragma unroll
    for (int rr = 0; rr < 16; ++rr) acc[rr] = fmaf(ea[rr][k], wv, acc[rr]);
  }
#pragma unroll
  for (int rr = 0; rr < 16; ++rr) hidv[rr][j] = ssp_f(acc[rr]);
  __syncthreads();
  float b2j = b2[j];
#pragma unroll
  for (int rr = 0; rr < 16; ++rr) acc[rr] = b2j;
  for (int k = 0; k < NF; ++k) {
    float wv = w2[k * NF + j];
#pragma unroll
    for (int rr = 0; rr < 16; ++rr) acc[rr] = fmaf(hidv[rr][k], wv, acc[rr]);
  }
#pragma unroll
  for (int rr = 0; rr < 16; ++rr) {
    int s = rbase + rr;
    if (s < TROWS) {
      float d = ((float)s - 1.0f) * h;
      float C = 0.5f * (cosf(d * (float)M_PI / CUTOFF) + 1.0f);
      table[(size_t)s * NF + j] = acc[rr] * C;
    }
  }
}

// ---------------- x1 = h @ cf_w1 (8 nodes per block) ----------------
__global__ void k_x1(const float* __restrict__ h, const float* __restrict__ w,
                     float* __restrict__ x1) {
  __shared__ float hs[8][HID];
  int i0 = blockIdx.x * 8;
  int j = threadIdx.x;
#pragma unroll
  for (int m = 0; m < 8; ++m) hs[m][j] = h[(size_t)(i0 + m) * HID + j];
  __syncthreads();
  float acc[8] = {0.f, 0.f, 0.f, 0.f, 0.f, 0.f, 0.f, 0.f};
  for (int k = 0; k < HID; ++k) {
    float wv = w[k * NF + j];
#pragma unroll
    for (int m = 0; m < 8; ++m) acc[m] = fmaf(hs[m][k], wv, acc[m]);
  }
#pragma unroll
  for (int m = 0; m < 8; ++m) x1[(size_t)(i0 + m) * NF + j] = acc[m];
}

// ---------------- per-molecule edge kernel: LDS-resident cubic table ----------------
__global__ void __launch_bounds__(512) k_edge_mol(
    const float* __restrict__ ftb, const int* __restrict__ ei,
    const float* __restrict__ tbl, const float* __restrict__ x1,
    float* __restrict__ agg) {
  __shared__ float stab[TROWS * NF];  // 82,944 B
  __shared__ float sx1[NPG * NF];     // 20,480 B
  __shared__ float sagg[NPG * NF];    // 20,480 B
  __shared__ float sft[EPM];          // 2,560 B
  __shared__ int   src_[EPM];         // 2,560 B   (row<<16 | col)
  int g = blockIdx.x;
  int a0 = g * NPG;
  int t = threadIdx.x;

  // stage table, x1; zero sagg; stage edge meta
  const float4* tin = (const float4*)tbl;
  float4* st4 = (float4*)stab;
  for (int i = t; i < TROWS * NF / 4; i += 512) st4[i] = tin[i];
  const float4* xin = (const float4*)(x1 + (size_t)a0 * NF);
  float4* sx4 = (float4*)sx1;
  float4* sa4 = (float4*)sagg;
  const float4 z4 = make_float4(0.f, 0.f, 0.f, 0.f);
  for (int i = t; i < NPG * NF / 4; i += 512) {
    sx4[i] = xin[i];
    sa4[i] = z4;
  }
  int ebase = a0 * DEG;
  for (int i = t; i < EPM; i += 512) {
    sft[i] = ftb[ebase + i];
    src_[i] = ((ei[ebase + i] - a0) << 16) | (ei[E_EDGES + ebase + i] - a0);
  }
  __syncthreads();

  int wave = t >> 6, lane = t & 63;
  const float2* tab2 = (const float2*)stab;
  const float2* sx2 = (const float2*)sx1;
  for (int eo0 = wave * 2; eo0 < EPM; eo0 += 16) {
#pragma unroll
    for (int u = 0; u < 2; ++u) {
      int eo = eo0 + u;
      float ft = sft[eo];
      int i0 = min((int)ft, TBL2 - 2);
      float tt = ft - (float)i0;
      int rc = src_[eo];
      // Catmull-Rom weights (wave-uniform)
      float t2 = tt * tt, t3 = t2 * tt;
      float w0 = 0.5f * (-t3 + 2.f * t2 - tt);
      float w1 = 0.5f * (3.f * t3 - 5.f * t2 + 2.f);
      float w2 = 0.5f * (-3.f * t3 + 4.f * t2 + tt);
      float w3 = 0.5f * (t3 - t2);
      int base = i0 * (NF / 2) + lane;  // stored rows i0 .. i0+3 == grid rows i0-1..i0+2
      float2 p0 = tab2[base];
      float2 p1 = tab2[base + (NF / 2)];
      float2 p2 = tab2[base + 2 * (NF / 2)];
      float2 p3 = tab2[base + 3 * (NF / 2)];
      float fx = w0 * p0.x;
      fx = fmaf(w1, p1.x, fx);
      fx = fmaf(w2, p2.x, fx);
      fx = fmaf(w3, p3.x, fx);
      float fy = w0 * p0.y;
      fy = fmaf(w1, p1.y, fy);
      fy = fmaf(w2, p2.y, fy);
      fy = fmaf(w3, p3.y, fy);
      float2 xv = sx2[(rc >> 16) * (NF / 2) + lane];
      int cbase = (rc & 0xffff) * NF + 2 * lane;
      atomicAdd(&sagg[cbase + 0], xv.x * fx);
      atomicAdd(&sagg[cbase + 1], xv.y * fy);
    }
  }
  __syncthreads();
  float4* aout = (float4*)(agg + (size_t)a0 * NF);
  for (int i = t; i < NPG * NF / 4; i += 512) aout[i] = sa4[i];
}

// ---------------- node update: h += (ssp(agg@cf_w2+b2)) @ lin_w + lin_b (8 nodes) ----------------
__global__ void k_update(const float* __restrict__ agg, const float* __restrict__ w2,
                         const float* __restrict__ b2, const float* __restrict__ lw,
                         const float* __restrict__ lb, float* __restrict__ h) {
  __shared__ float s[8][NF];
  __shared__ float u[8][NF];
  int i0 = blockIdx.x * 8;
  int j = threadIdx.x;
#pragma unroll
  for (int m = 0; m < 8; ++m) s[m][j] = agg[(size_t)(i0 + m) * NF + j];
  __syncthreads();
  float bj = b2[j];
  float acc[8];
#pragma unroll
  for (int m = 0; m < 8; ++m) acc[m] = bj;
  for (int k = 0; k < NF; ++k) {
    float wv = w2[k * HID + j];
#pragma unroll
    for (int m = 0; m < 8; ++m) acc[m] = fmaf(s[m][k], wv, acc[m]);
  }
#pragma unroll
  for (int m = 0; m < 8; ++m) u[m][j] = ssp_f(acc[m]);
  __syncthreads();
  float lbj = lb[j];
#pragma unroll
  for (int m = 0; m < 8; ++m) acc[m] = lbj;
  for (int k = 0; k < HID; ++k) {
    float wv = lw[k * HID + j];
#pragma unroll
    for (int m = 0; m < 8; ++m) acc[m] = fmaf(u[m][k], wv, acc[m]);
  }
#pragma unroll
  for (int m = 0; m < 8; ++m) h[(size_t)(i0 + m) * HID + j] += acc[m];
}

// ---------------- head ----------------
__global__ void k_head(const float* __restrict__ h, const float* __restrict__ hw1,
                       const float* __restrict__ hb1, const float* __restrict__ hw2,
                       const float* __restrict__ hb2, const int* __restrict__ batch,
                       float* __restrict__ out) {
  __shared__ float hs[4][HID];
  int i0 = blockIdx.x * 4;
  int j = threadIdx.x;  // 0..63
  for (int idx = j; idx < 4 * HID; idx += 64) hs[idx >> 7][idx & 127] = h[(size_t)i0 * HID + idx];
  __syncthreads();
  float bj = hb1[j];
  float acc[4];
#pragma unroll
  for (int m = 0; m < 4; ++m) acc[m] = bj;
  for (int k = 0; k < HID; ++k) {
    float wv = hw1[k * 64 + j];
#pragma unroll
    for (int m = 0; m < 4; ++m) acc[m] = fmaf(hs[m][k], wv, acc[m]);
  }
  float w2v = hw2[j];
  float b2v = hb2[0];
  float ysum = 0.f;
#pragma unroll
  for (int m = 0; m < 4; ++m) {
    float p = ssp_f(acc[m]) * w2v;
    for (int off = 32; off > 0; off >>= 1) p += __shfl_down(p, off);
    if (j == 0) ysum += p + b2v;
  }
  if (j == 0) atomicAdd(&out[batch[i0]], ysum);
}

extern "C" void kernel_launch(void* const* d_in, const int* in_sizes, int n_in,
                              void* d_out, int out_size, void* d_ws, size_t ws_size,
                              hipStream_t stream) {
  const float* pos    = (const float*)d_in[0];
  const float* emb    = (const float*)d_in[1];
  const float* mlp_w1 = (const float*)d_in[2];
  const float* mlp_b1 = (const float*)d_in[3];
  const float* mlp_w2 = (const float*)d_in[4];
  const float* mlp_b2 = (const float*)d_in[5];
  const float* cf_w1  = (const float*)d_in[6];
  const float* cf_w2  = (const float*)d_in[7];
  const float* cf_b2  = (const float*)d_in[8];
  const float* lin_w  = (const float*)d_in[9];
  const float* lin_b  = (const float*)d_in[10];
  const float* hw1    = (const float*)d_in[11];
  const float* hb1    = (const float*)d_in[12];
  const float* hw2    = (const float*)d_in[13];
  const float* hb2    = (const float*)d_in[14];
  const int*   z      = (const int*)d_in[15];
  const int*   batch  = (const int*)d_in[16];
  const int*   ei     = (const int*)d_in[17];

  float* ws  = (float*)d_ws;
  float* ftb  = ws;                          // E
  float* h    = ftb + E_EDGES;               // N*HID
  float* x1   = h + (size_t)N_ATOMS * HID;   // N*NF
  float* agg  = x1 + (size_t)N_ATOMS * NF;   // N*NF
  float* tbl  = agg + (size_t)N_ATOMS * NF;  // 3*TROWS*NF
  size_t need = ((size_t)E_EDGES + 3ull * N_ATOMS * HID + 3ull * TROWS * NF) * 4ull;
  if (ws_size < need) return;

  k_dist<<<(E_EDGES + 255) / 256, 256, 0, stream>>>(pos, ei, ftb);
  k_embed<<<(N_ATOMS * HID + 255) / 256, 256, 0, stream>>>(emb, z, h);
  k_table<<<dim3((TROWS + 15) / 16, 3), NF, 0, stream>>>(mlp_w1, mlp_b1, mlp_w2, mlp_b2, tbl);
  for (int l = 0; l < 3; ++l) {
    k_x1<<<N_ATOMS / 8, 128, 0, stream>>>(h, cf_w1 + (size_t)l * HID * NF, x1);
    k_edge_mol<<<G_GRAPHS, 512, 0, stream>>>(ftb, ei, tbl + (size_t)l * TROWS * NF, x1, agg);
    k_update<<<N_ATOMS / 8, 128, 0, stream>>>(agg, cf_w2 + (size_t)l * NF * HID,
                                              cf_b2 + (size_t)l * HID,
                                              lin_w + (size_t)l * HID * HID,
                                              lin_b + (size_t)l * HID, h);
  }
  hipMemsetAsync(d_out, 0, G_GRAPHS * 4, stream);
  k_head<<<N_ATOMS / 4, 64, 0, stream>>>(h, hw1, hb1, hw2, hb2, batch, (float*)d_out);
}

// Round 5
// 438.627 us; speedup vs baseline: 2.1445x; 2.1445x over previous
//
#include <hip/hip_runtime.h>
#include <math.h>

#define N_ATOMS 20000
#define G_GRAPHS 500
#define NPG 40
#define DEG 16
#define E_EDGES (N_ATOMS * DEG)
#define EPM (NPG * DEG)          // 640 edges per molecule
#define HID 128
#define NF 128
#define TBL2 160                 // cubic-interp table grid points
#define TROWS (TBL2 + 2)         // +1 extrapolated row each end (Catmull-Rom)
#define CUTOFF 10.0f
#define LOG2F_ 0.6931471805599453f

__device__ __forceinline__ float ssp_f(float x) {
  float ax = fabsf(x);
  return fmaxf(x, 0.0f) + log1pf(expf(-ax)) - LOG2F_;
}

// ---------------- distances -> pre-scaled table coordinate ----------------
__global__ void k_dist(const float* __restrict__ pos, const int* __restrict__ ei,
                       float* __restrict__ ftb) {
  int e = blockIdx.x * blockDim.x + threadIdx.x;
  if (e >= E_EDGES) return;
  int r = ei[e], c = ei[E_EDGES + e];
  float dx = pos[3 * r + 0] - pos[3 * c + 0];
  float dy = pos[3 * r + 1] - pos[3 * c + 1];
  float dz = pos[3 * r + 2] - pos[3 * c + 2];
  ftb[e] = sqrtf(dx * dx + dy * dy + dz * dz) * ((float)(TBL2 - 1) / CUTOFF);
}

// ---------------- embedding gather ----------------
__global__ void k_embed(const float* __restrict__ emb, const int* __restrict__ z,
                        float* __restrict__ h) {
  int t = blockIdx.x * blockDim.x + threadIdx.x;
  if (t >= N_ATOMS * HID) return;
  int i = t >> 7, c = t & 127;
  h[t] = emb[z[i] * HID + c];
}

// ---- filter tables (all 3 layers); stored row s = grid row s-1, d=(s-1)*h ----
__global__ void k_table(const float* __restrict__ w1_, const float* __restrict__ b1_,
                        const float* __restrict__ w2_, const float* __restrict__ b2_,
                        float* __restrict__ table_) {
  __shared__ float ea[16][NF];
  __shared__ float hidv[16][NF];
  int l = blockIdx.y;
  const float* w1 = w1_ + (size_t)l * NF * NF;
  const float* b1 = b1_ + (size_t)l * NF;
  const float* w2 = w2_ + (size_t)l * NF * NF;
  const float* b2 = b2_ + (size_t)l * NF;
  float* table = table_ + (size_t)l * TROWS * NF;
  int j = threadIdx.x;
  int rbase = blockIdx.x * 16;
  const float h = CUTOFF / (float)(TBL2 - 1);
  const float delta = CUTOFF / (float)(NF - 1);
  const float coeff = -0.5f / (delta * delta);
#pragma unroll
  for (int rr = 0; rr < 16; ++rr) {
    float d = ((float)(rbase + rr) - 1.0f) * h;
    float t = d - delta * (float)j;
    ea[rr][j] = expf(coeff * t * t);
  }
  __syncthreads();
  float b1j = b1[j];
  float acc[16];
#pragma unroll
  for (int rr = 0; rr < 16; ++rr) acc[rr] = b1j;
  for (int k = 0; k < NF; ++k) {
    float wv = w1[k * NF + j];
#pragma unroll
    for (int rr = 0; rr < 16; ++rr) acc[rr] = fmaf(ea[rr][k], wv, acc[rr]);
  }
#pragma unroll
  for (int rr = 0; rr < 16; ++rr) hidv[rr][j] = ssp_f(acc[rr]);
  __syncthreads();
  float b2j = b2[j];
#pragma unroll
  for (int rr = 0; rr < 16; ++rr) acc[rr] = b2j;
  for (int k = 0; k < NF; ++k) {
    float wv = w2[k * NF + j];
#pragma unroll
    for (int rr = 0; rr < 16; ++rr) acc[rr] = fmaf(hidv[rr][k], wv, acc[rr]);
  }
#pragma unroll
  for (int rr = 0; rr < 16; ++rr) {
    int s = rbase + rr;
    if (s < TROWS) {
      float d = ((float)s - 1.0f) * h;
      float C = 0.5f * (cosf(d * (float)M_PI / CUTOFF) + 1.0f);
      table[(size_t)s * NF + j] = acc[rr] * C;
    }
  }
}

// ---------------- one-time CSR-by-destination build (deterministic) ----------------
// Packs per-edge (row 6b | i0 8b | frac 18b) into u32, grouped by dst atom.
__global__ void k_csr(const float* __restrict__ ftb, const int* __restrict__ ei,
                      unsigned* __restrict__ ginfo, int* __restrict__ gstart) {
  __shared__ int cnt[NPG];
  __shared__ int pfx[NPG + 1];
  __shared__ unsigned epk[EPM];  // packed edge info in edge order
  __shared__ short ecol[EPM];
  int g = blockIdx.x;
  int a0 = g * NPG;
  int t = threadIdx.x;  // 0..63 (single wave)
  if (t < NPG) cnt[t] = 0;
  __syncthreads();
  int ebase = a0 * DEG;
  for (int i = t; i < EPM; i += 64) {
    int col = ei[E_EDGES + ebase + i] - a0;
    int row = ei[ebase + i] - a0;
    float ft = ftb[ebase + i];
    int i0 = min((int)ft, TBL2 - 2);
    float tt = ft - (float)i0;
    unsigned ttf = (unsigned)(tt * 262144.0f);
    if (ttf > 262143u) ttf = 262143u;
    epk[i] = ((unsigned)row << 26) | ((unsigned)i0 << 18) | ttf;
    ecol[i] = (short)col;
    atomicAdd(&cnt[col], 1);
  }
  __syncthreads();
  if (t == 0) {
    int s = 0;
    for (int a = 0; a < NPG; ++a) { pfx[a] = s; s += cnt[a]; }
    pfx[NPG] = s;
    // deterministic serial fill from LDS
    int pos[NPG];
    for (int a = 0; a < NPG; ++a) pos[a] = pfx[a];
    for (int e = 0; e < EPM; ++e) {
      int c = ecol[e];
      ginfo[(size_t)g * EPM + (pos[c]++)] = epk[e];
    }
  }
  if (t < NPG) gstart[g * NPG + t] = pfx[t];
  __syncthreads();
}

// ---------------- x1 = h @ cf_w1 (8 nodes per block) ----------------
__global__ void k_x1(const float* __restrict__ h, const float* __restrict__ w,
                     float* __restrict__ x1) {
  __shared__ float hs[8][HID];
  int i0 = blockIdx.x * 8;
  int j = threadIdx.x;
#pragma unroll
  for (int m = 0; m < 8; ++m) hs[m][j] = h[(size_t)(i0 + m) * HID + j];
  __syncthreads();
  float acc[8] = {0.f, 0.f, 0.f, 0.f, 0.f, 0.f, 0.f, 0.f};
  for (int k = 0; k < HID; ++k) {
    float wv = w[k * NF + j];
#pragma unroll
    for (int m = 0; m < 8; ++m) acc[m] = fmaf(hs[m][k], wv, acc[m]);
  }
#pragma unroll
  for (int m = 0; m < 8; ++m) x1[(size_t)(i0 + m) * NF + j] = acc[m];
}

// ---------------- aggregation: owned-reduction, no atomics ----------------
// grid = G*2 blocks: (molecule, channel-half). 512 thr = 8 waves.
// Each wave owns atoms a = wave, wave+8, ...; accumulates in registers.
__global__ void __launch_bounds__(512) k_agg(
    const unsigned* __restrict__ ginfo, const int* __restrict__ gstart,
    const float* __restrict__ tbl, const float* __restrict__ x1,
    float* __restrict__ agg) {
  __shared__ float sx1[NPG * 64];   // 10 KB (this block's channel-half)
  __shared__ unsigned smeta[EPM];   // 2.5 KB
  __shared__ int sstart[NPG + 1];
  int g = blockIdx.x >> 1;
  int ch0 = (blockIdx.x & 1) * 64;
  int a0 = g * NPG;
  int t = threadIdx.x;

  // stage x1 slice (rows a0..a0+39, cols ch0..ch0+63)
  for (int i = t; i < NPG * 16; i += 512) {
    int r = i >> 4, c4 = i & 15;
    ((float4*)sx1)[i] = *(const float4*)(x1 + (size_t)(a0 + r) * NF + ch0 + c4 * 4);
  }
  const unsigned* gin = ginfo + (size_t)g * EPM;
  for (int i = t; i < EPM; i += 512) smeta[i] = gin[i];
  if (t < NPG) sstart[t] = gstart[g * NPG + t];
  if (t == 0) sstart[NPG] = EPM;
  __syncthreads();

  int wave = t >> 6, lane = t & 63;
  for (int a = wave; a < NPG; a += 8) {
    int kb = sstart[a], ke = sstart[a + 1];
    float acc = 0.f;
    int k = kb;
    for (; k + 1 < ke; k += 2) {
      unsigned m0 = smeta[k], m1 = smeta[k + 1];
      int r0 = m0 >> 26, r1 = m1 >> 26;
      int i00 = (m0 >> 18) & 255, i01 = (m1 >> 18) & 255;
      float t0 = (float)(m0 & 262143u) * (1.0f / 262144.0f);
      float t1 = (float)(m1 & 262143u) * (1.0f / 262144.0f);
      const float* b0 = tbl + (size_t)i00 * NF + ch0 + lane;
      const float* b1 = tbl + (size_t)i01 * NF + ch0 + lane;
      float p00 = b0[0], p01 = b0[NF], p02 = b0[2 * NF], p03 = b0[3 * NF];
      float p10 = b1[0], p11 = b1[NF], p12 = b1[2 * NF], p13 = b1[3 * NF];
      float xa = sx1[r0 * 64 + lane];
      float xb = sx1[r1 * 64 + lane];
      float q2 = t0 * t0, q3 = q2 * t0;
      float w0 = 0.5f * (-q3 + 2.f * q2 - t0);
      float w1 = 0.5f * (3.f * q3 - 5.f * q2 + 2.f);
      float w2 = 0.5f * (-3.f * q3 + 4.f * q2 + t0);
      float w3 = 0.5f * (q3 - q2);
      float f0 = w0 * p00;
      f0 = fmaf(w1, p01, f0);
      f0 = fmaf(w2, p02, f0);
      f0 = fmaf(w3, p03, f0);
      float s2 = t1 * t1, s3 = s2 * t1;
      float v0 = 0.5f * (-s3 + 2.f * s2 - t1);
      float v1 = 0.5f * (3.f * s3 - 5.f * s2 + 2.f);
      float v2 = 0.5f * (-3.f * s3 + 4.f * s2 + t1);
      float v3 = 0.5f * (s3 - s2);
      float f1 = v0 * p10;
      f1 = fmaf(v1, p11, f1);
      f1 = fmaf(v2, p12, f1);
      f1 = fmaf(v3, p13, f1);
      acc = fmaf(xa, f0, acc);
      acc = fmaf(xb, f1, acc);
    }
    if (k < ke) {
      unsigned m0 = smeta[k];
      int r0 = m0 >> 26;
      int i00 = (m0 >> 18) & 255;
      float t0 = (float)(m0 & 262143u) * (1.0f / 262144.0f);
      const float* b0 = tbl + (size_t)i00 * NF + ch0 + lane;
      float p00 = b0[0], p01 = b0[NF], p02 = b0[2 * NF], p03 = b0[3 * NF];
      float xa = sx1[r0 * 64 + lane];
      float q2 = t0 * t0, q3 = q2 * t0;
      float w0 = 0.5f * (-q3 + 2.f * q2 - t0);
      float w1 = 0.5f * (3.f * q3 - 5.f * q2 + 2.f);
      float w2 = 0.5f * (-3.f * q3 + 4.f * q2 + t0);
      float w3 = 0.5f * (q3 - q2);
      float f0 = w0 * p00;
      f0 = fmaf(w1, p01, f0);
      f0 = fmaf(w2, p02, f0);
      f0 = fmaf(w3, p03, f0);
      acc = fmaf(xa, f0, acc);
    }
    agg[(size_t)(a0 + a) * NF + ch0 + lane] = acc;
  }
}

// ---------------- node update: h += (ssp(agg@cf_w2+b2)) @ lin_w + lin_b ----------------
__global__ void k_update(const float* __restrict__ agg, const float* __restrict__ w2,
                         const float* __restrict__ b2, const float* __restrict__ lw,
                         const float* __restrict__ lb, float* __restrict__ h) {
  __shared__ float s[8][NF];
  __shared__ float u[8][NF];
  int i0 = blockIdx.x * 8;
  int j = threadIdx.x;
#pragma unroll
  for (int m = 0; m < 8; ++m) s[m][j] = agg[(size_t)(i0 + m) * NF + j];
  __syncthreads();
  float bj = b2[j];
  float acc[8];
#pragma unroll
  for (int m = 0; m < 8; ++m) acc[m] = bj;
  for (int k = 0; k < NF; ++k) {
    float wv = w2[k * HID + j];
#pragma unroll
    for (int m = 0; m < 8; ++m) acc[m] = fmaf(s[m][k], wv, acc[m]);
  }
#pragma unroll
  for (int m = 0; m < 8; ++m) u[m][j] = ssp_f(acc[m]);
  __syncthreads();
  float lbj = lb[j];
#pragma unroll
  for (int m = 0; m < 8; ++m) acc[m] = lbj;
  for (int k = 0; k < HID; ++k) {
    float wv = lw[k * HID + j];
#pragma unroll
    for (int m = 0; m < 8; ++m) acc[m] = fmaf(u[m][k], wv, acc[m]);
  }
#pragma unroll
  for (int m = 0; m < 8; ++m) h[(size_t)(i0 + m) * HID + j] += acc[m];
}

// ---------------- head ----------------
__global__ void k_head(const float* __restrict__ h, const float* __restrict__ hw1,
                       const float* __restrict__ hb1, const float* __restrict__ hw2,
                       const float* __restrict__ hb2, const int* __restrict__ batch,
                       float* __restrict__ out) {
  __shared__ float hs[4][HID];
  int i0 = blockIdx.x * 4;
  int j = threadIdx.x;  // 0..63
  for (int idx = j; idx < 4 * HID; idx += 64) hs[idx >> 7][idx & 127] = h[(size_t)i0 * HID + idx];
  __syncthreads();
  float bj = hb1[j];
  float acc[4];
#pragma unroll
  for (int m = 0; m < 4; ++m) acc[m] = bj;
  for (int k = 0; k < HID; ++k) {
    float wv = hw1[k * 64 + j];
#pragma unroll
    for (int m = 0; m < 4; ++m) acc[m] = fmaf(hs[m][k], wv, acc[m]);
  }
  float w2v = hw2[j];
  float b2v = hb2[0];
  float ysum = 0.f;
#pragma unroll
  for (int m = 0; m < 4; ++m) {
    float p = ssp_f(acc[m]) * w2v;
    for (int off = 32; off > 0; off >>= 1) p += __shfl_down(p, off);
    if (j == 0) ysum += p + b2v;
  }
  if (j == 0) atomicAdd(&out[batch[i0]], ysum);
}

extern "C" void kernel_launch(void* const* d_in, const int* in_sizes, int n_in,
                              void* d_out, int out_size, void* d_ws, size_t ws_size,
                              hipStream_t stream) {
  const float* pos    = (const float*)d_in[0];
  const float* emb    = (const float*)d_in[1];
  const float* mlp_w1 = (const float*)d_in[2];
  const float* mlp_b1 = (const float*)d_in[3];
  const float* mlp_w2 = (const float*)d_in[4];
  const float* mlp_b2 = (const float*)d_in[5];
  const float* cf_w1  = (const float*)d_in[6];
  const float* cf_w2  = (const float*)d_in[7];
  const float* cf_b2  = (const float*)d_in[8];
  const float* lin_w  = (const float*)d_in[9];
  const float* lin_b  = (const float*)d_in[10];
  const float* hw1    = (const float*)d_in[11];
  const float* hb1    = (const float*)d_in[12];
  const float* hw2    = (const float*)d_in[13];
  const float* hb2    = (const float*)d_in[14];
  const int*   z      = (const int*)d_in[15];
  const int*   batch  = (const int*)d_in[16];
  const int*   ei     = (const int*)d_in[17];

  float* ws = (float*)d_ws;
  float* h      = ws;                                  // N*HID
  float* x1     = h + (size_t)N_ATOMS * HID;           // N*NF
  float* agg    = x1 + (size_t)N_ATOMS * NF;           // N*NF (ftb aliases here)
  float* ftb    = agg;                                 // consumed before first k_agg
  float* tbl    = agg + (size_t)N_ATOMS * NF;          // 3*TROWS*NF
  int*   gstart = (int*)(tbl + 3ull * TROWS * NF);     // G*NPG
  unsigned* ginfo = (unsigned*)(gstart + G_GRAPHS * NPG);  // E
  size_t need = (3ull * N_ATOMS * HID + 3ull * TROWS * NF + G_GRAPHS * NPG + E_EDGES) * 4ull;
  if (ws_size < need) return;

  k_dist<<<(E_EDGES + 255) / 256, 256, 0, stream>>>(pos, ei, ftb);
  k_embed<<<(N_ATOMS * HID + 255) / 256, 256, 0, stream>>>(emb, z, h);
  k_table<<<dim3((TROWS + 15) / 16, 3), NF, 0, stream>>>(mlp_w1, mlp_b1, mlp_w2, mlp_b2, tbl);
  k_csr<<<G_GRAPHS, 64, 0, stream>>>(ftb, ei, ginfo, gstart);
  for (int l = 0; l < 3; ++l) {
    k_x1<<<N_ATOMS / 8, 128, 0, stream>>>(h, cf_w1 + (size_t)l * HID * NF, x1);
    k_agg<<<G_GRAPHS * 2, 512, 0, stream>>>(ginfo, gstart, tbl + (size_t)l * TROWS * NF, x1, agg);
    k_update<<<N_ATOMS / 8, 128, 0, stream>>>(agg, cf_w2 + (size_t)l * NF * HID,
                                              cf_b2 + (size_t)l * HID,
                                              lin_w + (size_t)l * HID * HID,
                                              lin_b + (size_t)l * HID, h);
  }
  hipMemsetAsync(d_out, 0, G_GRAPHS * 4, stream);
  k_head<<<N_ATOMS / 4, 64, 0, stream>>>(h, hw1, hb1, hw2, hb2, batch, (float*)d_out);
}

// Round 6
// 370.248 us; speedup vs baseline: 2.5405x; 1.1847x over previous
//
#include <hip/hip_runtime.h>
#include <math.h>

#define N_ATOMS 20000
#define G_GRAPHS 500
#define NPG 40
#define DEG 16
#define E_EDGES (N_ATOMS * DEG)
#define EPM (NPG * DEG)          // 640 edges per molecule
#define HID 128
#define NF 128
#define TBL2 160                 // cubic-interp table grid points
#define TROWS (TBL2 + 2)         // +1 extrapolated row each end (Catmull-Rom)
#define CUTOFF 10.0f
#define LOG2F_ 0.6931471805599453f

__device__ __forceinline__ float ssp_f(float x) {
  float ax = fabsf(x);
  return fmaxf(x, 0.0f) + log1pf(expf(-ax)) - LOG2F_;
}

// ---------------- embedding gather ----------------
__global__ void k_embed(const float* __restrict__ emb, const int* __restrict__ z,
                        float* __restrict__ h) {
  int t = blockIdx.x * blockDim.x + threadIdx.x;
  if (t >= N_ATOMS * HID) return;
  int i = t >> 7, c = t & 127;
  h[t] = emb[z[i] * HID + c];
}

// ---- filter tables (all 3 layers); stored row s = grid row s-1, d=(s-1)*h ----
__global__ void k_table(const float* __restrict__ w1_, const float* __restrict__ b1_,
                        const float* __restrict__ w2_, const float* __restrict__ b2_,
                        float* __restrict__ table_) {
  __shared__ float ea[16][NF];
  __shared__ float hidv[16][NF];
  int l = blockIdx.y;
  const float* w1 = w1_ + (size_t)l * NF * NF;
  const float* b1 = b1_ + (size_t)l * NF;
  const float* w2 = w2_ + (size_t)l * NF * NF;
  const float* b2 = b2_ + (size_t)l * NF;
  float* table = table_ + (size_t)l * TROWS * NF;
  int j = threadIdx.x;
  int rbase = blockIdx.x * 16;
  const float h = CUTOFF / (float)(TBL2 - 1);
  const float delta = CUTOFF / (float)(NF - 1);
  const float coeff = -0.5f / (delta * delta);
#pragma unroll
  for (int rr = 0; rr < 16; ++rr) {
    float d = ((float)(rbase + rr) - 1.0f) * h;
    float t = d - delta * (float)j;
    ea[rr][j] = expf(coeff * t * t);
  }
  __syncthreads();
  float b1j = b1[j];
  float acc[16];
#pragma unroll
  for (int rr = 0; rr < 16; ++rr) acc[rr] = b1j;
  for (int k = 0; k < NF; ++k) {
    float wv = w1[k * NF + j];
#pragma unroll
    for (int rr = 0; rr < 16; ++rr) acc[rr] = fmaf(ea[rr][k], wv, acc[rr]);
  }
#pragma unroll
  for (int rr = 0; rr < 16; ++rr) hidv[rr][j] = ssp_f(acc[rr]);
  __syncthreads();
  float b2j = b2[j];
#pragma unroll
  for (int rr = 0; rr < 16; ++rr) acc[rr] = b2j;
  for (int k = 0; k < NF; ++k) {
    float wv = w2[k * NF + j];
#pragma unroll
    for (int rr = 0; rr < 16; ++rr) acc[rr] = fmaf(hidv[rr][k], wv, acc[rr]);
  }
#pragma unroll
  for (int rr = 0; rr < 16; ++rr) {
    int s = rbase + rr;
    if (s < TROWS) {
      float d = ((float)s - 1.0f) * h;
      float C = 0.5f * (cosf(d * (float)M_PI / CUTOFF) + 1.0f);
      table[(size_t)s * NF + j] = acc[rr] * C;
    }
  }
}

// ---- one-time: distances + CSR-by-destination (deterministic, parallel fill) ----
// pack per edge: row 6b | i0 8b | frac 18b
__global__ void k_csr(const float* __restrict__ pos, const int* __restrict__ ei,
                      unsigned* __restrict__ ginfo, int* __restrict__ gstart) {
  __shared__ float spos[NPG * 3];
  __shared__ int cnt[NPG];
  __shared__ int pfx[NPG + 1];
  __shared__ unsigned epk[EPM];
  __shared__ unsigned char ecol[EPM];
  __shared__ unsigned ssort[EPM];
  int g = blockIdx.x;
  int a0 = g * NPG;
  int t = threadIdx.x;  // 64 threads
  for (int i = t; i < NPG * 3; i += 64) spos[i] = pos[a0 * 3 + i];
  if (t < NPG) cnt[t] = 0;
  __syncthreads();
  int ebase = a0 * DEG;
  const float tscale = (float)(TBL2 - 1) / CUTOFF;
  for (int i = t; i < EPM; i += 64) {
    int r = ei[ebase + i] - a0;
    int c = ei[E_EDGES + ebase + i] - a0;
    float dx = spos[3 * r + 0] - spos[3 * c + 0];
    float dy = spos[3 * r + 1] - spos[3 * c + 1];
    float dz = spos[3 * r + 2] - spos[3 * c + 2];
    float ft = sqrtf(dx * dx + dy * dy + dz * dz) * tscale;
    int i0 = min((int)ft, TBL2 - 2);
    float tt = ft - (float)i0;
    unsigned ttf = (unsigned)(tt * 262144.0f);
    if (ttf > 262143u) ttf = 262143u;
    epk[i] = ((unsigned)r << 26) | ((unsigned)i0 << 18) | ttf;
    ecol[i] = (unsigned char)c;
    atomicAdd(&cnt[c], 1);
  }
  __syncthreads();
  if (t == 0) {
    int s = 0;
    for (int a = 0; a < NPG; ++a) { pfx[a] = s; s += cnt[a]; }
    pfx[NPG] = s;
  }
  __syncthreads();
  // lane-per-atom order-preserving fill (broadcast LDS reads)
  if (t < NPG) {
    int p = pfx[t];
    for (int e = 0; e < EPM; ++e) {
      unsigned pk = epk[e];   // broadcast
      if ((int)ecol[e] == t) ssort[p++] = pk;
    }
  }
  __syncthreads();
  for (int i = t; i < EPM; i += 64) ginfo[(size_t)g * EPM + i] = ssort[i];
  if (t < NPG) gstart[g * NPG + t] = pfx[t];
}

// ---------------- fused per-molecule layer ----------------
// phases: stage h -> x1=h@W1 -> edge agg (owned, no atomics) ->
//         s=ssp(agg@W2+b2) -> x=s@lw+lb -> h+=x
__global__ void __launch_bounds__(512) k_layer(
    float* __restrict__ hbuf, const unsigned* __restrict__ ginfo,
    const int* __restrict__ gstart, const float* __restrict__ tbl,
    const float* __restrict__ w1, const float* __restrict__ w2,
    const float* __restrict__ b2, const float* __restrict__ lw,
    const float* __restrict__ lb) {
  __shared__ float sh[NPG][HID];   // 20,480 B : h (residual kept)
  __shared__ float sb[NPG][HID];   // 20,480 B : x1, then u
  __shared__ float sg[NPG][HID];   // 20,480 B : agg
  __shared__ unsigned smeta[EPM];  //  2,560 B
  __shared__ int sstart[NPG + 1];
  int g = blockIdx.x;
  int a0 = g * NPG;
  int t = threadIdx.x;

  {
    const float4* hin = (const float4*)(hbuf + (size_t)a0 * HID);
    float4* sh4 = (float4*)sh;
    for (int i = t; i < NPG * HID / 4; i += 512) sh4[i] = hin[i];
    const unsigned* gin = ginfo + (size_t)g * EPM;
    for (int i = t; i < EPM; i += 512) smeta[i] = gin[i];
    if (t < NPG) sstart[t] = gstart[g * NPG + t];
    if (t == 0) sstart[NPG] = EPM;
  }
  __syncthreads();

  int j = t & 127, ar = t >> 7;  // ar in 0..3; rows ar+4m, m=0..9

  // ---- x1 = sh @ w1 -> sb ----
  {
    float acc[10];
#pragma unroll
    for (int m = 0; m < 10; ++m) acc[m] = 0.f;
    for (int k = 0; k < HID; k += 4) {
      float wa = w1[(k + 0) * NF + j];
      float wb = w1[(k + 1) * NF + j];
      float wc = w1[(k + 2) * NF + j];
      float wd = w1[(k + 3) * NF + j];
#pragma unroll
      for (int m = 0; m < 10; ++m) {
        float4 hv = *(const float4*)&sh[ar + 4 * m][k];
        acc[m] = fmaf(hv.x, wa, acc[m]);
        acc[m] = fmaf(hv.y, wb, acc[m]);
        acc[m] = fmaf(hv.z, wc, acc[m]);
        acc[m] = fmaf(hv.w, wd, acc[m]);
      }
    }
#pragma unroll
    for (int m = 0; m < 10; ++m) sb[ar + 4 * m][j] = acc[m];
  }
  __syncthreads();

  // ---- edge aggregation: wave owns atoms wave, wave+8, ... ----
  {
    int wave = t >> 6, lane = t & 63;
    const float2* sb2 = (const float2*)sb;
    for (int a = wave; a < NPG; a += 8) {
      int kb = sstart[a], ke = sstart[a + 1];
      float accx = 0.f, accy = 0.f;
      int k = kb;
      for (; k + 1 < ke; k += 2) {
        unsigned m0 = smeta[k], m1 = smeta[k + 1];
        int r0 = m0 >> 26, r1 = m1 >> 26;
        int i00 = (m0 >> 18) & 255, i01 = (m1 >> 18) & 255;
        float t0 = (float)(m0 & 262143u) * (1.0f / 262144.0f);
        float t1 = (float)(m1 & 262143u) * (1.0f / 262144.0f);
        const float2* b0 = (const float2*)(tbl + (size_t)i00 * NF) + lane;
        const float2* b1 = (const float2*)(tbl + (size_t)i01 * NF) + lane;
        float2 p00 = b0[0], p01 = b0[64], p02 = b0[128], p03 = b0[192];
        float2 p10 = b1[0], p11 = b1[64], p12 = b1[128], p13 = b1[192];
        float2 xa = sb2[r0 * 64 + lane];
        float2 xb = sb2[r1 * 64 + lane];
        float q2 = t0 * t0, q3 = q2 * t0;
        float w0 = 0.5f * (-q3 + 2.f * q2 - t0);
        float w1_ = 0.5f * (3.f * q3 - 5.f * q2 + 2.f);
        float w2_ = 0.5f * (-3.f * q3 + 4.f * q2 + t0);
        float w3 = 0.5f * (q3 - q2);
        float fx = w0 * p00.x; fx = fmaf(w1_, p01.x, fx); fx = fmaf(w2_, p02.x, fx); fx = fmaf(w3, p03.x, fx);
        float fy = w0 * p00.y; fy = fmaf(w1_, p01.y, fy); fy = fmaf(w2_, p02.y, fy); fy = fmaf(w3, p03.y, fy);
        float s2 = t1 * t1, s3 = s2 * t1;
        float v0 = 0.5f * (-s3 + 2.f * s2 - t1);
        float v1 = 0.5f * (3.f * s3 - 5.f * s2 + 2.f);
        float v2 = 0.5f * (-3.f * s3 + 4.f * s2 + t1);
        float v3 = 0.5f * (s3 - s2);
        float gx = v0 * p10.x; gx = fmaf(v1, p11.x, gx); gx = fmaf(v2, p12.x, gx); gx = fmaf(v3, p13.x, gx);
        float gy = v0 * p10.y; gy = fmaf(v1, p11.y, gy); gy = fmaf(v2, p12.y, gy); gy = fmaf(v3, p13.y, gy);
        accx = fmaf(xa.x, fx, accx); accy = fmaf(xa.y, fy, accy);
        accx = fmaf(xb.x, gx, accx); accy = fmaf(xb.y, gy, accy);
      }
      if (k < ke) {
        unsigned m0 = smeta[k];
        int r0 = m0 >> 26;
        int i00 = (m0 >> 18) & 255;
        float t0 = (float)(m0 & 262143u) * (1.0f / 262144.0f);
        const float2* b0 = (const float2*)(tbl + (size_t)i00 * NF) + lane;
        float2 p00 = b0[0], p01 = b0[64], p02 = b0[128], p03 = b0[192];
        float2 xa = sb2[r0 * 64 + lane];
        float q2 = t0 * t0, q3 = q2 * t0;
        float w0 = 0.5f * (-q3 + 2.f * q2 - t0);
        float w1_ = 0.5f * (3.f * q3 - 5.f * q2 + 2.f);
        float w2_ = 0.5f * (-3.f * q3 + 4.f * q2 + t0);
        float w3 = 0.5f * (q3 - q2);
        float fx = w0 * p00.x; fx = fmaf(w1_, p01.x, fx); fx = fmaf(w2_, p02.x, fx); fx = fmaf(w3, p03.x, fx);
        float fy = w0 * p00.y; fy = fmaf(w1_, p01.y, fy); fy = fmaf(w2_, p02.y, fy); fy = fmaf(w3, p03.y, fy);
        accx = fmaf(xa.x, fx, accx); accy = fmaf(xa.y, fy, accy);
      }
      ((float2*)sg[a])[lane] = make_float2(accx, accy);
    }
  }
  __syncthreads();

  // ---- s = ssp(sg @ w2 + b2) -> sb ----
  {
    float bj = b2[j];
    float acc[10];
#pragma unroll
    for (int m = 0; m < 10; ++m) acc[m] = bj;
    for (int k = 0; k < NF; k += 4) {
      float wa = w2[(k + 0) * HID + j];
      float wb = w2[(k + 1) * HID + j];
      float wc = w2[(k + 2) * HID + j];
      float wd = w2[(k + 3) * HID + j];
#pragma unroll
      for (int m = 0; m < 10; ++m) {
        float4 gv = *(const float4*)&sg[ar + 4 * m][k];
        acc[m] = fmaf(gv.x, wa, acc[m]);
        acc[m] = fmaf(gv.y, wb, acc[m]);
        acc[m] = fmaf(gv.z, wc, acc[m]);
        acc[m] = fmaf(gv.w, wd, acc[m]);
      }
    }
#pragma unroll
    for (int m = 0; m < 10; ++m) sb[ar + 4 * m][j] = ssp_f(acc[m]);
  }
  __syncthreads();

  // ---- x = sb @ lw + lb; h += x (global write) ----
  {
    float bj = lb[j];
    float acc[10];
#pragma unroll
    for (int m = 0; m < 10; ++m) acc[m] = bj;
    for (int k = 0; k < HID; k += 4) {
      float wa = lw[(k + 0) * HID + j];
      float wb = lw[(k + 1) * HID + j];
      float wc = lw[(k + 2) * HID + j];
      float wd = lw[(k + 3) * HID + j];
#pragma unroll
      for (int m = 0; m < 10; ++m) {
        float4 uv = *(const float4*)&sb[ar + 4 * m][k];
        acc[m] = fmaf(uv.x, wa, acc[m]);
        acc[m] = fmaf(uv.y, wb, acc[m]);
        acc[m] = fmaf(uv.z, wc, acc[m]);
        acc[m] = fmaf(uv.w, wd, acc[m]);
      }
    }
#pragma unroll
    for (int m = 0; m < 10; ++m) {
      int a = ar + 4 * m;
      hbuf[(size_t)(a0 + a) * HID + j] = sh[a][j] + acc[m];
    }
  }
}

// ---------------- head ----------------
__global__ void k_head(const float* __restrict__ h, const float* __restrict__ hw1,
                       const float* __restrict__ hb1, const float* __restrict__ hw2,
                       const float* __restrict__ hb2, const int* __restrict__ batch,
                       float* __restrict__ out) {
  __shared__ float hs[4][HID];
  int i0 = blockIdx.x * 4;
  int j = threadIdx.x;  // 0..63
  for (int idx = j; idx < 4 * HID; idx += 64) hs[idx >> 7][idx & 127] = h[(size_t)i0 * HID + idx];
  __syncthreads();
  float bj = hb1[j];
  float acc[4];
#pragma unroll
  for (int m = 0; m < 4; ++m) acc[m] = bj;
  for (int k = 0; k < HID; ++k) {
    float wv = hw1[k * 64 + j];
#pragma unroll
    for (int m = 0; m < 4; ++m) acc[m] = fmaf(hs[m][k], wv, acc[m]);
  }
  float w2v = hw2[j];
  float b2v = hb2[0];
  float ysum = 0.f;
#pragma unroll
  for (int m = 0; m < 4; ++m) {
    float p = ssp_f(acc[m]) * w2v;
    for (int off = 32; off > 0; off >>= 1) p += __shfl_down(p, off);
    if (j == 0) ysum += p + b2v;
  }
  if (j == 0) atomicAdd(&out[batch[i0]], ysum);
}

extern "C" void kernel_launch(void* const* d_in, const int* in_sizes, int n_in,
                              void* d_out, int out_size, void* d_ws, size_t ws_size,
                              hipStream_t stream) {
  const float* pos    = (const float*)d_in[0];
  const float* emb    = (const float*)d_in[1];
  const float* mlp_w1 = (const float*)d_in[2];
  const float* mlp_b1 = (const float*)d_in[3];
  const float* mlp_w2 = (const float*)d_in[4];
  const float* mlp_b2 = (const float*)d_in[5];
  const float* cf_w1  = (const float*)d_in[6];
  const float* cf_w2  = (const float*)d_in[7];
  const float* cf_b2  = (const float*)d_in[8];
  const float* lin_w  = (const float*)d_in[9];
  const float* lin_b  = (const float*)d_in[10];
  const float* hw1    = (const float*)d_in[11];
  const float* hb1    = (const float*)d_in[12];
  const float* hw2    = (const float*)d_in[13];
  const float* hb2    = (const float*)d_in[14];
  const int*   z      = (const int*)d_in[15];
  const int*   batch  = (const int*)d_in[16];
  const int*   ei     = (const int*)d_in[17];

  float* ws = (float*)d_ws;
  float* h      = ws;                                      // N*HID
  float* tbl    = h + (size_t)N_ATOMS * HID;               // 3*TROWS*NF
  int*   gstart = (int*)(tbl + 3ull * TROWS * NF);         // G*NPG
  unsigned* ginfo = (unsigned*)(gstart + G_GRAPHS * NPG);  // E
  size_t need = ((size_t)N_ATOMS * HID + 3ull * TROWS * NF + G_GRAPHS * NPG + E_EDGES) * 4ull;
  if (ws_size < need) return;

  k_embed<<<(N_ATOMS * HID + 255) / 256, 256, 0, stream>>>(emb, z, h);
  k_table<<<dim3((TROWS + 15) / 16, 3), NF, 0, stream>>>(mlp_w1, mlp_b1, mlp_w2, mlp_b2, tbl);
  k_csr<<<G_GRAPHS, 64, 0, stream>>>(pos, ei, ginfo, gstart);
  for (int l = 0; l < 3; ++l) {
    k_layer<<<G_GRAPHS, 512, 0, stream>>>(h, ginfo, gstart, tbl + (size_t)l * TROWS * NF,
                                          cf_w1 + (size_t)l * HID * NF,
                                          cf_w2 + (size_t)l * NF * HID,
                                          cf_b2 + (size_t)l * HID,
                                          lin_w + (size_t)l * HID * HID,
                                          lin_b + (size_t)l * HID);
  }
  hipMemsetAsync(d_out, 0, G_GRAPHS * 4, stream);
  k_head<<<N_ATOMS / 4, 64, 0, stream>>>(h, hw1, hb1, hw2, hb2, batch, (float*)d_out);
}